// Round 1
// baseline (2597.401 us; speedup 1.0000x reference)
//
#include <hip/hip_runtime.h>

#define NA 50000
#define NE 1600000
#define HH 128
#define D1 129
#define EPS 1e-3f

// ---- workspace layout (float offsets) ----
#define OFF_A1   0
#define OFF_C1   129
#define OFF_A2   258
#define OFF_C2   387
#define OFF_WEFF 516
#define OFF_DVEC (OFF_WEFF + 384*129)
#define OFF_Q1   (OFF_DVEC + 129)
#define OFF_Q2   (OFF_Q1 + 128*128)
#define OFF_q1   (OFF_Q2 + 128*128)
#define OFF_q2   (OFF_q1 + 128)
#define OFF_QF   (OFF_q2 + 128)
#define OFF_qf   (OFF_QF + 128*128)
#define OFF_PI   (((OFF_qf + 128) + 3) & ~3)
#define OFF_PJ   (OFF_PI + NA*D1)
#define OFF_ACC  (OFF_PJ + NA*D1)
// total floats = OFF_ACC + NA*HH  (~19.4M floats = 77.6 MB)

// BN -> affine params
__global__ void k_affine(const float* __restrict__ g1, const float* __restrict__ b1,
                         const float* __restrict__ m1, const float* __restrict__ v1,
                         const float* __restrict__ g2, const float* __restrict__ b2,
                         const float* __restrict__ m2, const float* __restrict__ v2,
                         float* __restrict__ ws) {
    for (int idx = threadIdx.x; idx < 2 * D1; idx += blockDim.x) {
        if (idx < D1) {
            float a = g1[idx] * rsqrtf(v1[idx] + EPS);
            ws[OFF_A1 + idx] = a;
            ws[OFF_C1 + idx] = b1[idx] - m1[idx] * a;
        } else {
            int n = idx - D1;
            float a = g2[n] * rsqrtf(v2[n] + EPS);
            ws[OFF_A2 + n] = a;
            ws[OFF_C2 + n] = b2[n] - m2[n] * a;
        }
    }
}

// Weff[k][n] = a2[n] * sum_t W1[k][t]*a1[t]*W2[t][n]; dvec[n] = a2[n]*sum_t c1[t]*W2[t][n] + c2[n]
__global__ void k_weff(const float* __restrict__ W1, const float* __restrict__ W2,
                       float* __restrict__ ws) {
    int idx = blockIdx.x * blockDim.x + threadIdx.x;
    if (idx >= 384 * D1 + D1) return;
    const float* a1 = ws + OFF_A1;
    const float* c1 = ws + OFF_C1;
    const float* a2 = ws + OFF_A2;
    const float* c2 = ws + OFF_C2;
    if (idx < 384 * D1) {
        int k = idx / D1, n = idx % D1;
        float s = 0.f;
        for (int t = 0; t < D1; ++t)
            s += W1[(size_t)k * D1 + t] * a1[t] * W2[(size_t)t * D1 + n];
        ws[OFF_WEFF + idx] = s * a2[n];
    } else {
        int n = idx - 384 * D1;
        float s = 0.f;
        for (int t = 0; t < D1; ++t)
            s += c1[t] * W2[(size_t)t * D1 + n];
        ws[OFF_DVEC + n] = s * a2[n] + c2[n];
    }
}

// Q_l = I + w1@w2 ; q_l = b1@w2 + b2  (for each residual layer)
__global__ void k_resid(const float* __restrict__ r1w1, const float* __restrict__ r1b1,
                        const float* __restrict__ r1w2, const float* __restrict__ r1b2,
                        const float* __restrict__ r2w1, const float* __restrict__ r2b1,
                        const float* __restrict__ r2w2, const float* __restrict__ r2b2,
                        float* __restrict__ ws) {
    int idx = blockIdx.x * blockDim.x + threadIdx.x;
    if (idx >= 2 * (128 * 128 + 128)) return;
    int layer = idx / (128 * 128 + 128);
    int r = idx % (128 * 128 + 128);
    const float* w1 = layer ? r2w1 : r1w1;
    const float* b1 = layer ? r2b1 : r1b1;
    const float* w2 = layer ? r2w2 : r1w2;
    const float* b2 = layer ? r2b2 : r1b2;
    float* Q = ws + (layer ? OFF_Q2 : OFF_Q1);
    float* q = ws + (layer ? OFF_q2 : OFF_q1);
    if (r < 128 * 128) {
        int i = r >> 7, j = r & 127;
        float s = (i == j) ? 1.f : 0.f;
        for (int t = 0; t < 128; ++t)
            s += w1[i * 128 + t] * w2[t * 128 + j];
        Q[r] = s;
    } else {
        int j = r - 128 * 128;
        float s = b2[j];
        for (int t = 0; t < 128; ++t)
            s += b1[t] * w2[t * 128 + j];
        q[j] = s;
    }
}

// Qf = Q1@Q2 ; qf = q1@Q2 + q2
__global__ void k_qf(float* __restrict__ ws) {
    int idx = blockIdx.x * blockDim.x + threadIdx.x;
    if (idx >= 128 * 128 + 128) return;
    const float* Q1 = ws + OFF_Q1;
    const float* Q2 = ws + OFF_Q2;
    if (idx < 128 * 128) {
        int i = idx >> 7, j = idx & 127;
        float s = 0.f;
        for (int m = 0; m < 128; ++m)
            s += Q1[i * 128 + m] * Q2[m * 128 + j];
        ws[OFF_QF + idx] = s;
    } else {
        int j = idx - 128 * 128;
        const float* q1 = ws + OFF_q1;
        float s = ws[OFF_q2 + j];
        for (int m = 0; m < 128; ++m)
            s += q1[m] * Q2[m * 128 + j];
        ws[OFF_qf + j] = s;
    }
}

// generic C[M][N] = (A (+A2)) @ W + bias   with K=128, lda=128
__global__ __launch_bounds__(256) void k_gemm128(
    const float* __restrict__ A, const float* __restrict__ A2,
    const float* __restrict__ W, int ldw, const float* __restrict__ bias,
    float* __restrict__ C, int ldc, int M, int N) {
    __shared__ float As[32][128];
    __shared__ float Ws[128][32];
    int t = threadIdx.x;
    int m0 = blockIdx.x * 32, n0 = blockIdx.y * 32;
    for (int idx = t; idx < 32 * 32; idx += 256) {
        int r = idx >> 5, c4 = idx & 31;
        float4 v = make_float4(0.f, 0.f, 0.f, 0.f);
        if (m0 + r < M) {
            v = ((const float4*)(A + (size_t)(m0 + r) * 128))[c4];
            if (A2) {
                float4 w = ((const float4*)(A2 + (size_t)(m0 + r) * 128))[c4];
                v.x += w.x; v.y += w.y; v.z += w.z; v.w += w.w;
            }
        }
        *(float4*)&As[r][c4 * 4] = v;
    }
    for (int idx = t; idx < 128 * 32; idx += 256) {
        int k = idx >> 5, n = idx & 31;
        Ws[k][n] = (n0 + n < N) ? W[(size_t)k * ldw + n0 + n] : 0.f;
    }
    __syncthreads();
    int ty = t >> 5, tx = t & 31;
    float acc[4] = {0.f, 0.f, 0.f, 0.f};
    for (int k = 0; k < 128; ++k) {
        float w = Ws[k][tx];
#pragma unroll
        for (int i = 0; i < 4; ++i) acc[i] += As[ty * 4 + i][k] * w;
    }
    int n = n0 + tx;
    float bv = (bias && n < N) ? bias[n] : 0.f;
#pragma unroll
    for (int i = 0; i < 4; ++i) {
        int r = m0 + ty * 4 + i;
        if (r < M && n < N) C[(size_t)r * ldc + n] = acc[i] + bv;
    }
}

// edge kernel: 32 edges/block. y2 = bond@Wmid + Pi[i] + Pj[j]; msg = y2[0]*y2[1:]; atomicAdd into acc
__global__ __launch_bounds__(256) void k_edge(
    const float* __restrict__ bond, const int* __restrict__ idx_i,
    const int* __restrict__ idx_j, const float* __restrict__ Wmid,
    const float* __restrict__ Pi, const float* __restrict__ Pj,
    float* __restrict__ accb) {
    __shared__ float bond_s[32][128];
    __shared__ float wm_s[64][128];
    __shared__ float wg_s[128];
    __shared__ float gate_s[32];
    __shared__ int ii_s[32], jj_s[32];
    int t = threadIdx.x;
    size_t e0 = (size_t)blockIdx.x * 32;
    if (t < 32) ii_s[t] = idx_i[e0 + t];
    else if (t < 64) jj_s[t - 32] = idx_j[e0 + (t - 32)];
    if (t < 128) wg_s[t] = Wmid[(size_t)t * D1];  // gate column (col 0)
    for (int idx = t; idx < 32 * 32; idx += 256) {
        int r = idx >> 5, c4 = idx & 31;
        *(float4*)&bond_s[r][c4 * 4] = ((const float4*)(bond + (e0 + r) * 128))[c4];
    }
    __syncthreads();
    // gate: 8 threads per edge, 16 MACs each, shfl reduce
    {
        int e = t >> 3, seg = t & 7;
        float p = 0.f;
#pragma unroll
        for (int k = 0; k < 16; ++k) p += bond_s[e][seg * 16 + k] * wg_s[seg * 16 + k];
        p += __shfl_xor(p, 1);
        p += __shfl_xor(p, 2);
        p += __shfl_xor(p, 4);
        if (seg == 0) {
            gate_s[e] = p + Pi[(size_t)ii_s[e] * D1] + Pj[(size_t)jj_s[e] * D1];
        }
    }
    int ty = t >> 5, tx = t & 31;
    float acc[4][4] = {};
    for (int kc = 0; kc < 128; kc += 64) {
        __syncthreads();
        for (int idx = t; idx < 64 * 128; idx += 256) {
            int kk = idx >> 7, n = idx & 127;
            wm_s[kk][n] = Wmid[(size_t)(kc + kk) * D1 + 1 + n];
        }
        __syncthreads();
        for (int kk4 = 0; kk4 < 16; ++kk4) {
            float bb[4][4];
#pragma unroll
            for (int i = 0; i < 4; ++i) {
                float4 v = *(const float4*)&bond_s[ty * 4 + i][kc + kk4 * 4];
                bb[i][0] = v.x; bb[i][1] = v.y; bb[i][2] = v.z; bb[i][3] = v.w;
            }
#pragma unroll
            for (int u = 0; u < 4; ++u) {
                float w0 = wm_s[kk4 * 4 + u][tx];
                float w1 = wm_s[kk4 * 4 + u][tx + 32];
                float w2 = wm_s[kk4 * 4 + u][tx + 64];
                float w3 = wm_s[kk4 * 4 + u][tx + 96];
#pragma unroll
                for (int i = 0; i < 4; ++i) {
                    acc[i][0] += bb[i][u] * w0;
                    acc[i][1] += bb[i][u] * w1;
                    acc[i][2] += bb[i][u] * w2;
                    acc[i][3] += bb[i][u] * w3;
                }
            }
        }
    }
    // epilogue: add gathered Pi/Pj, gate-multiply, scatter
#pragma unroll
    for (int i = 0; i < 4; ++i) {
        int e = ty * 4 + i;
        int ii = ii_s[e], jj = jj_s[e];
        float g = gate_s[e];
        size_t pib = (size_t)ii * D1 + 1, pjb = (size_t)jj * D1 + 1;
#pragma unroll
        for (int c = 0; c < 4; ++c) {
            int n = tx + c * 32;
            float y = acc[i][c] + Pi[pib + n] + Pj[pjb + n];
            atomicAdd(&accb[(size_t)ii * 128 + n], g * y);
        }
    }
}

extern "C" void kernel_launch(void* const* d_in, const int* in_sizes, int n_in,
                              void* d_out, int out_size, void* d_ws, size_t ws_size,
                              hipStream_t stream) {
    const float* atom = (const float*)d_in[0];
    const float* bond = (const float*)d_in[1];
    const int* idx_i = (const int*)d_in[2];
    const int* idx_j = (const int*)d_in[3];
    const float* W1 = (const float*)d_in[4];
    const float* g1 = (const float*)d_in[5];
    const float* b1 = (const float*)d_in[6];
    const float* m1 = (const float*)d_in[7];
    const float* v1 = (const float*)d_in[8];
    const float* W2 = (const float*)d_in[9];
    const float* g2 = (const float*)d_in[10];
    const float* b2 = (const float*)d_in[11];
    const float* m2 = (const float*)d_in[12];
    const float* v2 = (const float*)d_in[13];
    const float* r1w1 = (const float*)d_in[14];
    const float* r1b1 = (const float*)d_in[15];
    const float* r1w2 = (const float*)d_in[16];
    const float* r1b2 = (const float*)d_in[17];
    const float* r2w1 = (const float*)d_in[18];
    const float* r2b1 = (const float*)d_in[19];
    const float* r2w2 = (const float*)d_in[20];
    const float* r2b2 = (const float*)d_in[21];
    float* ws = (float*)d_ws;
    float* out = (float*)d_out;

    k_affine<<<1, 256, 0, stream>>>(g1, b1, m1, v1, g2, b2, m2, v2, ws);
    k_weff<<<(384 * D1 + D1 + 255) / 256, 256, 0, stream>>>(W1, W2, ws);
    k_resid<<<(2 * (128 * 128 + 128) + 255) / 256, 256, 0, stream>>>(
        r1w1, r1b1, r1w2, r1b2, r2w1, r2b1, r2w2, r2b2, ws);
    k_qf<<<(128 * 128 + 128 + 255) / 256, 256, 0, stream>>>(ws);

    // Pi = atom @ Wtop + dvec ; Pj = atom @ Wbot
    dim3 gpi((NA + 31) / 32, (D1 + 31) / 32);
    k_gemm128<<<gpi, 256, 0, stream>>>(atom, nullptr, ws + OFF_WEFF, D1,
                                       ws + OFF_DVEC, ws + OFF_PI, D1, NA, D1);
    k_gemm128<<<gpi, 256, 0, stream>>>(atom, nullptr, ws + OFF_WEFF + 256 * D1, D1,
                                       nullptr, ws + OFF_PJ, D1, NA, D1);

    hipMemsetAsync(ws + OFF_ACC, 0, (size_t)NA * HH * sizeof(float), stream);

    k_edge<<<NE / 32, 256, 0, stream>>>(bond, idx_i, idx_j, ws + OFF_WEFF + 128 * D1,
                                        ws + OFF_PI, ws + OFF_PJ, ws + OFF_ACC);

    // out = (atom + acc) @ Qf + qf
    dim3 gfin((NA + 31) / 32, 4);
    k_gemm128<<<gfin, 256, 0, stream>>>(atom, ws + OFF_ACC, ws + OFF_QF, 128,
                                        ws + OFF_qf, out, 128, NA, HH);
}

// Round 2
// 2405.253 us; speedup vs baseline: 1.0799x; 1.0799x over previous
//
#include <hip/hip_runtime.h>

#define NA 50000
#define NE 1600000
#define HH 128
#define D1 129
#define EPS 1e-3f

typedef __bf16 bf16_t;
typedef bf16_t bf16x8 __attribute__((ext_vector_type(8)));
typedef bf16_t bf16x4 __attribute__((ext_vector_type(4)));
typedef float f32x4 __attribute__((ext_vector_type(4)));

// ---- workspace layout (float offsets) ----
#define OFF_A1   0
#define OFF_C1   129
#define OFF_A2   258
#define OFF_C2   387
#define OFF_WEFF 516
#define OFF_DVEC (OFF_WEFF + 384*129)          // 50052
#define OFF_Q1   (OFF_DVEC + 129)              // 50181
#define OFF_Q2   (OFF_Q1 + 128*128)
#define OFF_q1   (OFF_Q2 + 128*128)
#define OFF_q2   (OFF_q1 + 128)
#define OFF_QF   (OFF_q2 + 128)
#define OFF_qf   (OFF_QF + 128*128)
#define OFF_WMT  (((OFF_qf + 128) + 3) & ~3)   // WmidT bf16 [144][128] -> 9216 floats
#define OFF_WTT  (OFF_WMT + 9216)              // WtopT bf16 [144][128]
#define OFF_WBT  (OFF_WTT + 9216)              // WbotT bf16 [144][128]
#define OFF_QFT  (OFF_WBT + 9216)              // QfT  bf16 [128][128] -> 8192 floats
#define OFF_PI   (OFF_QFT + 8192)
#define OFF_PJ   (OFF_PI + NA*D1)
#define OFF_ACC  (OFF_PJ + NA*D1)
#define OFF_ACC2 (OFF_ACC + NA*HH)
// total ~19.5M floats = 78 MB

// ---------------- setup kernels (tiny) ----------------
__global__ void k_affine(const float* __restrict__ g1, const float* __restrict__ b1,
                         const float* __restrict__ m1, const float* __restrict__ v1,
                         const float* __restrict__ g2, const float* __restrict__ b2,
                         const float* __restrict__ m2, const float* __restrict__ v2,
                         float* __restrict__ ws) {
    for (int idx = threadIdx.x; idx < 2 * D1; idx += blockDim.x) {
        if (idx < D1) {
            float a = g1[idx] * rsqrtf(v1[idx] + EPS);
            ws[OFF_A1 + idx] = a;
            ws[OFF_C1 + idx] = b1[idx] - m1[idx] * a;
        } else {
            int n = idx - D1;
            float a = g2[n] * rsqrtf(v2[n] + EPS);
            ws[OFF_A2 + n] = a;
            ws[OFF_C2 + n] = b2[n] - m2[n] * a;
        }
    }
}

__global__ void k_weff(const float* __restrict__ W1, const float* __restrict__ W2,
                       float* __restrict__ ws) {
    int idx = blockIdx.x * blockDim.x + threadIdx.x;
    if (idx >= 384 * D1 + D1) return;
    const float* a1 = ws + OFF_A1;
    const float* c1 = ws + OFF_C1;
    const float* a2 = ws + OFF_A2;
    const float* c2 = ws + OFF_C2;
    if (idx < 384 * D1) {
        int k = idx / D1, n = idx % D1;
        float s = 0.f;
        for (int t = 0; t < D1; ++t)
            s += W1[(size_t)k * D1 + t] * a1[t] * W2[(size_t)t * D1 + n];
        ws[OFF_WEFF + idx] = s * a2[n];
    } else {
        int n = idx - 384 * D1;
        float s = 0.f;
        for (int t = 0; t < D1; ++t)
            s += c1[t] * W2[(size_t)t * D1 + n];
        ws[OFF_DVEC + n] = s * a2[n] + c2[n];
    }
}

__global__ void k_resid(const float* __restrict__ r1w1, const float* __restrict__ r1b1,
                        const float* __restrict__ r1w2, const float* __restrict__ r1b2,
                        const float* __restrict__ r2w1, const float* __restrict__ r2b1,
                        const float* __restrict__ r2w2, const float* __restrict__ r2b2,
                        float* __restrict__ ws) {
    int idx = blockIdx.x * blockDim.x + threadIdx.x;
    if (idx >= 2 * (128 * 128 + 128)) return;
    int layer = idx / (128 * 128 + 128);
    int r = idx % (128 * 128 + 128);
    const float* w1 = layer ? r2w1 : r1w1;
    const float* b1 = layer ? r2b1 : r1b1;
    const float* w2 = layer ? r2w2 : r1w2;
    const float* b2 = layer ? r2b2 : r1b2;
    float* Q = ws + (layer ? OFF_Q2 : OFF_Q1);
    float* q = ws + (layer ? OFF_q2 : OFF_q1);
    if (r < 128 * 128) {
        int i = r >> 7, j = r & 127;
        float s = (i == j) ? 1.f : 0.f;
        for (int t = 0; t < 128; ++t)
            s += w1[i * 128 + t] * w2[t * 128 + j];
        Q[r] = s;
    } else {
        int j = r - 128 * 128;
        float s = b2[j];
        for (int t = 0; t < 128; ++t)
            s += b1[t] * w2[t * 128 + j];
        q[j] = s;
    }
}

__global__ void k_qf(float* __restrict__ ws) {
    int idx = blockIdx.x * blockDim.x + threadIdx.x;
    if (idx >= 128 * 128 + 128) return;
    const float* Q1 = ws + OFF_Q1;
    const float* Q2 = ws + OFF_Q2;
    if (idx < 128 * 128) {
        int i = idx >> 7, j = idx & 127;
        float s = 0.f;
        for (int m = 0; m < 128; ++m)
            s += Q1[i * 128 + m] * Q2[m * 128 + j];
        ws[OFF_QF + idx] = s;
    } else {
        int j = idx - 128 * 128;
        const float* q1 = ws + OFF_q1;
        float s = ws[OFF_q2 + j];
        for (int m = 0; m < 128; ++m)
            s += q1[m] * Q2[m * 128 + j];
        ws[OFF_qf + j] = s;
    }
}

// pack transposed bf16 weights: WmidT/WtopT/WbotT [144][128] (row n = output col, k contiguous), QfT [128][128]
__global__ void k_pack(float* __restrict__ ws) {
    int idx = blockIdx.x * blockDim.x + threadIdx.x;
    const float* Weff = ws + OFF_WEFF;
    if (idx < 18432) {
        int n = idx >> 7, k = idx & 127;
        float v = (n < 128) ? Weff[(size_t)(128 + k) * D1 + n + 1]
                            : ((n == 128) ? Weff[(size_t)(128 + k) * D1] : 0.f);
        ((bf16_t*)(ws + OFF_WMT))[idx] = (bf16_t)v;
    } else if (idx < 2 * 18432) {
        int r = idx - 18432;
        int n = r >> 7, k = r & 127;
        float v = (n < D1) ? Weff[(size_t)k * D1 + n] : 0.f;
        ((bf16_t*)(ws + OFF_WTT))[r] = (bf16_t)v;
    } else if (idx < 3 * 18432) {
        int r = idx - 2 * 18432;
        int n = r >> 7, k = r & 127;
        float v = (n < D1) ? Weff[(size_t)(256 + k) * D1 + n] : 0.f;
        ((bf16_t*)(ws + OFF_WBT))[r] = (bf16_t)v;
    } else if (idx < 3 * 18432 + 16384) {
        int r = idx - 3 * 18432;
        int n = r >> 7, k = r & 127;
        ((bf16_t*)(ws + OFF_QFT))[r] = (bf16_t)ws[OFF_QF + k * 128 + n];
    }
}

// ---------------- MFMA dense GEMM: C[M][N] = (A + A2 + acc2*Pi') @ Wt^T + bias ----------------
// Wt is bf16 [ntiles*16][128], row n holds column n of W (k contiguous).
__global__ __launch_bounds__(256) void k_gemm_mfma(
    const float* __restrict__ A, const float* __restrict__ A2,
    const float* __restrict__ Pi, const float* __restrict__ acc2,
    const bf16_t* __restrict__ Wt, const float* __restrict__ bias,
    float* __restrict__ C, int ldc, int N, int ntiles, int M) {
    __shared__ __align__(16) bf16_t As[64][136];
    int t = threadIdx.x;
    int m0 = blockIdx.x * 64;
#pragma unroll
    for (int it = 0; it < 8; ++it) {
        int idx = t + 256 * it;
        int r = idx >> 5, c4 = idx & 31;
        int grow = m0 + r;
        float4 v = make_float4(0.f, 0.f, 0.f, 0.f);
        if (grow < M) {
            v = ((const float4*)(A + (size_t)grow * 128))[c4];
            if (A2) {
                float4 w = ((const float4*)(A2 + (size_t)grow * 128))[c4];
                v.x += w.x; v.y += w.y; v.z += w.z; v.w += w.w;
            }
            if (acc2) {
                float s = acc2[grow];
                const float* p = Pi + (size_t)grow * D1 + 1 + c4 * 4;
                v.x += s * p[0]; v.y += s * p[1]; v.z += s * p[2]; v.w += s * p[3];
            }
        }
        bf16x4 tmp;
        tmp[0] = (bf16_t)v.x; tmp[1] = (bf16_t)v.y; tmp[2] = (bf16_t)v.z; tmp[3] = (bf16_t)v.w;
        *(bf16x4*)&As[r][c4 * 4] = tmp;
    }
    __syncthreads();
    int lane = t & 63, w = t >> 6;
    int ll = lane & 15, quad = lane >> 4;
    bf16x8 a[4];
#pragma unroll
    for (int k = 0; k < 4; ++k)
        a[k] = *(const bf16x8*)&As[w * 16 + ll][k * 32 + quad * 8];
    for (int nt = 0; nt < ntiles; ++nt) {
        const bf16_t* bp = Wt + (size_t)(nt * 16 + ll) * 128 + quad * 8;
        f32x4 acc = {0.f, 0.f, 0.f, 0.f};
#pragma unroll
        for (int k = 0; k < 4; ++k) {
            bf16x8 b = *(const bf16x8*)(bp + k * 32);
            acc = __builtin_amdgcn_mfma_f32_16x16x32_bf16(a[k], b, acc, 0, 0, 0);
        }
        int col = nt * 16 + ll;
        if (col < N) {
            float bv = bias ? bias[col] : 0.f;
#pragma unroll
            for (int r = 0; r < 4; ++r) {
                int row = m0 + w * 16 + quad * 4 + r;
                if (row < M) C[(size_t)row * ldc + col] = acc[r] + bv;
            }
        }
    }
}

// ---------------- edge kernel: y2 = bond@Wmid + Pi[i] + Pj[j]; msg = y2[0]*y2[1:]; scatter ----------------
__global__ __launch_bounds__(256) void k_edge_mfma(
    const float* __restrict__ bond, const int* __restrict__ idx_i,
    const int* __restrict__ idx_j, const bf16_t* __restrict__ WmidT,
    const float* __restrict__ Pi, const float* __restrict__ Pj,
    float* __restrict__ accb, float* __restrict__ acc2) {
    __shared__ __align__(16) bf16_t As[64][136];
    __shared__ int ii_s[64], jj_s[64];
    int t = threadIdx.x;
    size_t e0 = (size_t)blockIdx.x * 64;
    if (t < 64) ii_s[t] = idx_i[e0 + t];
    else if (t < 128) jj_s[t - 64] = idx_j[e0 + (t - 64)];
#pragma unroll
    for (int it = 0; it < 8; ++it) {
        int idx = t + 256 * it;
        int r = idx >> 5, c4 = idx & 31;
        float4 v = ((const float4*)(bond + (e0 + r) * 128))[c4];
        bf16x4 tmp;
        tmp[0] = (bf16_t)v.x; tmp[1] = (bf16_t)v.y; tmp[2] = (bf16_t)v.z; tmp[3] = (bf16_t)v.w;
        *(bf16x4*)&As[r][c4 * 4] = tmp;
    }
    __syncthreads();
    int lane = t & 63, w = t >> 6;
    int ll = lane & 15, quad = lane >> 4;
    bf16x8 a[4];
#pragma unroll
    for (int k = 0; k < 4; ++k)
        a[k] = *(const bf16x8*)&As[w * 16 + ll][k * 32 + quad * 8];

    int ii[4], jj[4];
#pragma unroll
    for (int r = 0; r < 4; ++r) {
        int e = w * 16 + quad * 4 + r;
        ii[r] = ii_s[e];
        jj[r] = jj_s[e];
    }

    // gate tile (WmidT rows 128..143; row 128 = gate column, rest zero)
    f32x4 ag = {0.f, 0.f, 0.f, 0.f};
    {
        const bf16_t* bp = WmidT + (size_t)(128 + ll) * 128 + quad * 8;
#pragma unroll
        for (int k = 0; k < 4; ++k) {
            bf16x8 b = *(const bf16x8*)(bp + k * 32);
            ag = __builtin_amdgcn_mfma_f32_16x16x32_bf16(a[k], b, ag, 0, 0, 0);
        }
    }
    float g[4];
    int src = lane & 48;  // lane quad*16 holds the gate (col 0 of the tile)
#pragma unroll
    for (int r = 0; r < 4; ++r) {
        float v = ag[r];
        if (ll == 0) v += Pi[(size_t)ii[r] * D1] + Pj[(size_t)jj[r] * D1];
        g[r] = __shfl(v, src);
    }
    if (ll == 0) {
#pragma unroll
        for (int r = 0; r < 4; ++r) atomicAdd(&acc2[ii[r]], g[r]);
    }

    const float* pjb[4];
    float* ab[4];
#pragma unroll
    for (int r = 0; r < 4; ++r) {
        pjb[r] = Pj + (size_t)jj[r] * D1 + 1;
        ab[r] = accb + (size_t)ii[r] * 128;
    }

    for (int nt = 0; nt < 8; ++nt) {
        const bf16_t* bp = WmidT + (size_t)(nt * 16 + ll) * 128 + quad * 8;
        f32x4 acc = {0.f, 0.f, 0.f, 0.f};
#pragma unroll
        for (int k = 0; k < 4; ++k) {
            bf16x8 b = *(const bf16x8*)(bp + k * 32);
            acc = __builtin_amdgcn_mfma_f32_16x16x32_bf16(a[k], b, acc, 0, 0, 0);
        }
        int n = nt * 16 + ll;
#pragma unroll
        for (int r = 0; r < 4; ++r) {
            float y = acc[r] + pjb[r][n];
            atomicAdd(ab[r] + n, g[r] * y);
        }
    }
}

extern "C" void kernel_launch(void* const* d_in, const int* in_sizes, int n_in,
                              void* d_out, int out_size, void* d_ws, size_t ws_size,
                              hipStream_t stream) {
    const float* atom = (const float*)d_in[0];
    const float* bond = (const float*)d_in[1];
    const int* idx_i = (const int*)d_in[2];
    const int* idx_j = (const int*)d_in[3];
    const float* W1 = (const float*)d_in[4];
    const float* g1 = (const float*)d_in[5];
    const float* b1 = (const float*)d_in[6];
    const float* m1 = (const float*)d_in[7];
    const float* v1 = (const float*)d_in[8];
    const float* W2 = (const float*)d_in[9];
    const float* g2 = (const float*)d_in[10];
    const float* b2 = (const float*)d_in[11];
    const float* m2 = (const float*)d_in[12];
    const float* v2 = (const float*)d_in[13];
    const float* r1w1 = (const float*)d_in[14];
    const float* r1b1 = (const float*)d_in[15];
    const float* r1w2 = (const float*)d_in[16];
    const float* r1b2 = (const float*)d_in[17];
    const float* r2w1 = (const float*)d_in[18];
    const float* r2b1 = (const float*)d_in[19];
    const float* r2w2 = (const float*)d_in[20];
    const float* r2b2 = (const float*)d_in[21];
    float* ws = (float*)d_ws;
    float* out = (float*)d_out;

    k_affine<<<1, 256, 0, stream>>>(g1, b1, m1, v1, g2, b2, m2, v2, ws);
    k_weff<<<(384 * D1 + D1 + 255) / 256, 256, 0, stream>>>(W1, W2, ws);
    k_resid<<<(2 * (128 * 128 + 128) + 255) / 256, 256, 0, stream>>>(
        r1w1, r1b1, r1w2, r1b2, r2w1, r2b1, r2w2, r2b2, ws);
    k_qf<<<(128 * 128 + 128 + 255) / 256, 256, 0, stream>>>(ws);
    k_pack<<<(3 * 18432 + 16384 + 255) / 256, 256, 0, stream>>>(ws);

    // Pi = atom @ Wtop + dvec ; Pj = atom @ Wbot   (N=129)
    int gblocks = (NA + 63) / 64;
    k_gemm_mfma<<<gblocks, 256, 0, stream>>>(
        atom, nullptr, nullptr, nullptr, (const bf16_t*)(ws + OFF_WTT),
        ws + OFF_DVEC, ws + OFF_PI, D1, D1, 9, NA);
    k_gemm_mfma<<<gblocks, 256, 0, stream>>>(
        atom, nullptr, nullptr, nullptr, (const bf16_t*)(ws + OFF_WBT),
        nullptr, ws + OFF_PJ, D1, D1, 9, NA);

    hipMemsetAsync(ws + OFF_ACC, 0, (size_t)(NA * HH + NA) * sizeof(float), stream);

    k_edge_mfma<<<NE / 64, 256, 0, stream>>>(
        bond, idx_i, idx_j, (const bf16_t*)(ws + OFF_WMT),
        ws + OFF_PI, ws + OFF_PJ, ws + OFF_ACC, ws + OFF_ACC2);

    // out = (atom + acc + acc2*Pi') @ Qf + qf
    k_gemm_mfma<<<gblocks, 256, 0, stream>>>(
        atom, ws + OFF_ACC, ws + OFF_PI, ws + OFF_ACC2, (const bf16_t*)(ws + OFF_QFT),
        ws + OFF_qf, out, 128, 128, 8, NA);
}